// Round 13
// baseline (233.672 us; speedup 1.0000x reference)
//
#include <hip/hip_runtime.h>
#include <hip/hip_fp16.h>
#include <math.h>

typedef _Float16 half_t;
typedef __attribute__((ext_vector_type(2))) _Float16 f16x2;
typedef __attribute__((ext_vector_type(4))) _Float16 f16x4;
typedef __attribute__((ext_vector_type(8))) _Float16 f16x8;
typedef __attribute__((ext_vector_type(4))) float f32x4;

#define BPTT 32
#define BSZ 32
#define NTOK 2000
#define NTOKP 2048
#define NINP 1024
#define NHID 256
#define TB 1024  /* BPTT*BSZ */
#define NH2 65536
#define TCH 8          /* t-steps per chunk -> 4 chunks of 256 rows */
#define FUSED_LDS 25600
#define FRONT_LDS 24576
#define CVT_LDS 16512  /* 16x258 f32: occupancy-free for 256-thr blocks (cap 9>8) */

// LDS swizzle for 32-half (64B) rows; bijective; same fn on write+read.
__device__ __forceinline__ int swz(int row, int hoff) {
  return (row * 32 + hoff) ^ ((row & 7) << 3);
}

// ---------------- wfef transpose body v4: 16-h tile, 16.5KB LDS ----------------
// p in [0,4096): r = p>>4, h-slab = (p&15)*16. Reads 64B/row (sibling block
// covers the other half-line; L2/L3 absorb), stages f32[16][258] (store 2-way
// free, read uniform-min), writes 16 FULL 512B-contiguous WWT rows.
__device__ __forceinline__ void wfefT_body(int p, const float* __restrict__ wfef,
                                           half_t* __restrict__ wwt, char* smem) {
  float* tile = (float*)smem;  // 16 x 258 f32 = 16512 B
  const int r = p >> 4, h0 = (p & 15) * 16;
  const int tid = threadIdx.x;
  const float* src = wfef + (size_t)(r * 256) * 256 + h0;
#pragma unroll
  for (int i = 0; i < 4; i++) {
    int q = i * 256 + tid;          // 1024 quads: 256 c x 4 qi
    int c = q >> 2, qi = q & 3;     // qi -> h-local = 4qi..4qi+3
    f32x4 v = *(const f32x4*)(src + (size_t)c * 256 + qi * 4);
#pragma unroll
    for (int k = 0; k < 4; k++) tile[(qi * 4 + k) * 258 + c] = v[k];
  }
  __syncthreads();
  const int c8 = (tid & 31) * 8, hr = tid >> 5;  // hr 0..7
#pragma unroll
  for (int i = 0; i < 2; i++) {
    int hl = i * 8 + hr;
    f32x4 u0 = *(const f32x4*)&tile[hl * 258 + c8];
    f32x4 u1 = *(const f32x4*)&tile[hl * 258 + c8 + 4];
    f16x8 o;
#pragma unroll
    for (int j = 0; j < 4; j++) {
      o[j] = (half_t)u0[j];
      o[j + 4] = (half_t)u1[j];
    }
    *(f16x8*)(wwt + ((size_t)(h0 + hl) * 256 + r) * 256 + c8) = o;
  }
}

// -------- merged conversions + full wfef transpose (one dispatch) --------
__global__ void cvtAll_k(const float* __restrict__ input, half_t* __restrict__ A1hi,
                         half_t* __restrict__ A1lo, const float* __restrict__ RBF_w,
                         half_t* __restrict__ B1hi, half_t* __restrict__ B1lo,
                         const float* __restrict__ emb_w,
                         const float* __restrict__ wfef_b,
                         const float* __restrict__ dec_w, half_t* __restrict__ B2,
                         half_t* __restrict__ WBh, half_t* __restrict__ B4,
                         const float* __restrict__ wfef_w, half_t* __restrict__ WWT) {
  extern __shared__ char dsm[];
  if (blockIdx.x < 4096) {  // transpose first: longest role starts earliest
    wfefT_body(blockIdx.x, wfef_w, WWT, dsm);
    return;
  }
  int bid = blockIdx.x - 4096;
  if (bid < 16384) {
    const float* src;
    half_t *hi, *lo;
    int idx;
    if (bid < 8192) {
      src = input; hi = A1hi; lo = A1lo; idx = bid * 256 + threadIdx.x;
    } else {
      src = RBF_w; hi = B1hi; lo = B1lo; idx = (bid - 8192) * 256 + threadIdx.x;
    }
    int r = idx >> 11, c = idx & 2047;
    float v = (c < NTOK) ? src[(size_t)r * NTOK + c] : 0.f;
    half_t h = (half_t)v;
    hi[idx] = h;
    lo[idx] = (half_t)(v - (float)h);
    return;
  }
  int i = (bid - 16384) * 256 + threadIdx.x;
  if (i < 262144) { B2[i] = (half_t)emb_w[i]; return; }
  i -= 262144;
  if (i < 65536) { WBh[i] = (half_t)wfef_b[i]; return; }
  i -= 65536;
  int r = i >> 8, c = i & 255;
  B4[i] = (half_t)((r < NTOK) ? dec_w[(size_t)r * 256 + c] : 0.f);
}

// ---------------- 128x128 fp16 GEMM (256 thr), C = A @ B^T ----------------
// EP: 1 = half store (acc+bias) [obs]
template <int EP>
__global__ __launch_bounds__(256) void gemm128_k(const half_t* __restrict__ A,
                                                 const half_t* __restrict__ B,
                                                 void* __restrict__ C,
                                                 const float* __restrict__ bias, int K,
                                                 int ldc) {
  __shared__ half_t As[128 * 32];
  __shared__ half_t Bs[128 * 32];
  const int tid = threadIdx.x;
  const int lane = tid & 63, wave = tid >> 6;
  const int wr = wave >> 1, wc = wave & 1;
  const int row0 = blockIdx.x * 128, col0 = blockIdx.y * 128;
  const int srow = tid >> 2, sseg = tid & 3;
  const size_t aoff = (size_t)(row0 + srow) * K + sseg * 8;
  const size_t boff = (size_t)(col0 + srow) * K + sseg * 8;
  const int fr = lane & 15, fq = lane >> 4;

  f32x4 acc[4][4];
#pragma unroll
  for (int m = 0; m < 4; m++)
#pragma unroll
    for (int n = 0; n < 4; n++) acc[m][n] = (f32x4)(0.0f);

  for (int k0 = 0; k0 < K; k0 += 32) {
    f16x8 a0 = *(const f16x8*)(A + aoff + k0);
    f16x8 a1 = *(const f16x8*)(A + aoff + (size_t)64 * K + k0);
    f16x8 b0 = *(const f16x8*)(B + boff + k0);
    f16x8 b1 = *(const f16x8*)(B + boff + (size_t)64 * K + k0);
    __syncthreads();
    *(f16x8*)(As + swz(srow, sseg * 8)) = a0;
    *(f16x8*)(As + swz(srow + 64, sseg * 8)) = a1;
    *(f16x8*)(Bs + swz(srow, sseg * 8)) = b0;
    *(f16x8*)(Bs + swz(srow + 64, sseg * 8)) = b1;
    __syncthreads();
    f16x8 af[4], bf[4];
#pragma unroll
    for (int m = 0; m < 4; m++)
      af[m] = *(const f16x8*)(As + swz(wr * 64 + m * 16 + fr, fq * 8));
#pragma unroll
    for (int n = 0; n < 4; n++)
      bf[n] = *(const f16x8*)(Bs + swz(wc * 64 + n * 16 + fr, fq * 8));
#pragma unroll
    for (int m = 0; m < 4; m++)
#pragma unroll
      for (int n = 0; n < 4; n++)
        acc[m][n] = __builtin_amdgcn_mfma_f32_16x16x32_f16(af[m], bf[n], acc[m][n], 0, 0, 0);
  }

#pragma unroll
  for (int m = 0; m < 4; m++)
#pragma unroll
    for (int n = 0; n < 4; n++)
#pragma unroll
      for (int j = 0; j < 4; j++) {
        int gr = row0 + wr * 64 + m * 16 + fq * 4 + j;
        int gc = col0 + wc * 64 + n * 16 + fr;
        ((half_t*)C)[(size_t)gr * ldc + gc] = (half_t)(acc[m][n][j] + bias[gc]);
      }
}

// ---------------- tall-thin GEMM body: 256 rows x 128 cols, K=256, 1024 thr ----
// EP: 0 = half store (M precompute, ldc=NH2); 2 = f32 store (V); 3 = f32 + bias,
// col guard (decoder)
template <int EP>
__device__ __forceinline__ void gemmMC_body(const half_t* __restrict__ A,
                                            const half_t* __restrict__ B,
                                            void* __restrict__ C,
                                            const float* __restrict__ bias, int col0,
                                            int ldc, int nvalid, char* smem) {
  half_t* As = (half_t*)smem;            // 256x32 halfs = 16384 B
  half_t* Bs = (half_t*)(smem + 16384);  // 128x32 halfs = 8192 B
  const int tid = threadIdx.x;
  const int lane = tid & 63, wave = tid >> 6;  // 16 waves: 4 row x 4 col
  const int wr = wave >> 2, wc = wave & 3;     // wave tile 64 rows x 32 cols
  const int srow = tid >> 2, sseg = tid & 3;
  const int fr = lane & 15, fq = lane >> 4;
  const size_t aoff = (size_t)srow * 256 + sseg * 8;
  const size_t boff = (size_t)(col0 + (srow & 127)) * 256 + sseg * 8;

  f32x4 acc[4][2];
#pragma unroll
  for (int m = 0; m < 4; m++)
#pragma unroll
    for (int n = 0; n < 2; n++) acc[m][n] = (f32x4)(0.0f);

  for (int k0 = 0; k0 < 256; k0 += 32) {
    f16x8 a0 = *(const f16x8*)(A + aoff + k0);
    f16x8 b0;
    if (tid < 512) b0 = *(const f16x8*)(B + boff + k0);
    __syncthreads();
    *(f16x8*)(As + swz(srow, sseg * 8)) = a0;
    if (tid < 512) *(f16x8*)(Bs + swz(srow, sseg * 8)) = b0;
    __syncthreads();
    f16x8 af[4], bf[2];
#pragma unroll
    for (int m = 0; m < 4; m++)
      af[m] = *(const f16x8*)(As + swz(wr * 64 + m * 16 + fr, fq * 8));
#pragma unroll
    for (int n = 0; n < 2; n++)
      bf[n] = *(const f16x8*)(Bs + swz(wc * 32 + n * 16 + fr, fq * 8));
#pragma unroll
    for (int m = 0; m < 4; m++)
#pragma unroll
      for (int n = 0; n < 2; n++)
        acc[m][n] = __builtin_amdgcn_mfma_f32_16x16x32_f16(af[m], bf[n], acc[m][n], 0, 0, 0);
  }

#pragma unroll
  for (int m = 0; m < 4; m++)
#pragma unroll
    for (int n = 0; n < 2; n++)
#pragma unroll
      for (int j = 0; j < 4; j++) {
        int gr = wr * 64 + m * 16 + fq * 4 + j;
        int gc = col0 + wc * 32 + n * 16 + fr;
        if (EP == 0) {
          ((half_t*)C)[(size_t)gr * ldc + gc] = (half_t)acc[m][n][j];
        } else if (EP == 2) {
          ((float*)C)[(size_t)gr * ldc + gc] = acc[m][n][j];
        } else {
          if (gc < nvalid)
            ((float*)C)[(size_t)gr * ldc + gc] = acc[m][n][j] + bias[gc];
        }
      }
}

// ---------------- scan body: TCH steps, 1024 threads, 2 barriers/step ----------
__device__ void scan_body(const half_t* __restrict__ Mc, const float* __restrict__ V,
                          int t0, const float* __restrict__ bin,
                          float* __restrict__ bstate, half_t* __restrict__ BN,
                          float* __restrict__ bfinal, int b, char* smem) {
  float(*Vs)[256] = (float(*)[256])smem;                  // 8192 B
  float(*partial)[260] = (float(*)[260])(smem + 8192);    // 16640 B
  unsigned* bh2 = (unsigned*)(smem + 24832);              // 512 B
  const int tid = threadIdx.x;
  const int hh = tid >> 6, lane = tid & 63;
  const int hpar = lane >> 5, r8 = (lane & 31) * 8;

  if (tid < TCH * 64) {
    int vr = tid >> 6;
    *(f32x4*)&Vs[vr][lane * 4] =
        *(const f32x4*)(V + ((size_t)(t0 + vr) * 32 + b) * 256 + lane * 4);
  }
  if (tid < 128) {
    const float* bs = bin + b * 256 + tid * 2;
    union { f16x2 h; unsigned u; } z;
    z.h[0] = (half_t)bs[0];
    z.h[1] = (half_t)bs[1];
    bh2[tid] = z.u;
  }

  // lane covers h = hh*16 + hpar + 2k (k=0..7), r in [r8, r8+8)
  const half_t* mbase = Mc + (size_t)b * NH2 + (size_t)(hh * 16 + hpar) * 256 + r8;
  f16x8 cur[8], nxt[8];
#pragma unroll
  for (int k = 0; k < 8; k++) cur[k] = *(const f16x8*)(mbase + k * 512);
  __syncthreads();

  for (int tt = 0; tt < TCH; tt++) {
    const int tn = (tt < TCH - 1) ? tt + 1 : TCH - 1;
    const half_t* mb2 = mbase + (size_t)tn * 32 * NH2;
#pragma unroll
    for (int k = 0; k < 8; k++) nxt[k] = *(const f16x8*)(mb2 + k * 512);

    uint4 q0 = *(const uint4*)&bh2[hh * 8];
    uint4 q1 = *(const uint4*)&bh2[hh * 8 + 4];
    unsigned bu[8] = {q0.x, q0.y, q0.z, q0.w, q1.x, q1.y, q1.z, q1.w};
    const int sh = hpar * 16;
    half_t hv[8];
#pragma unroll
    for (int k = 0; k < 8; k++)
      hv[k] = __builtin_bit_cast(half_t, (unsigned short)(bu[k] >> sh));

    float a[8] = {0.f, 0.f, 0.f, 0.f, 0.f, 0.f, 0.f, 0.f};
#pragma unroll
    for (int k = 0; k < 8; k++)
#pragma unroll
      for (int j = 0; j < 8; j++) a[j] += (float)cur[k][j] * (float)hv[k];
#pragma unroll
    for (int j = 0; j < 8; j++) a[j] += __shfl_xor(a[j], 32);
    f32x4 st = hpar ? (f32x4){a[4], a[5], a[6], a[7]} : (f32x4){a[0], a[1], a[2], a[3]};
    *(f32x4*)&partial[hh][r8 + hpar * 4] = st;
    __syncthreads();  // B1: partials ready

    if (tid < 64) {  // single-wave normalize: lane owns r = tid*4 .. tid*4+3
      f32x4 s = *(const f32x4*)&Vs[tt][tid * 4];
#pragma unroll
      for (int g = 0; g < 16; g++) s += *(const f32x4*)&partial[g][tid * 4];
      float sq = s[0] * s[0] + s[1] * s[1] + s[2] * s[2] + s[3] * s[3];
#pragma unroll
      for (int o = 32; o > 0; o >>= 1) sq += __shfl_xor(sq, o);
      float inv = 1.0f / sqrtf(sq);
      f32x4 bn = {s[0] * inv, s[1] * inv, s[2] * inv, s[3] * inv};
      union { f16x2 h; unsigned u; } z0, z1;
      z0.h[0] = (half_t)bn[0]; z0.h[1] = (half_t)bn[1];
      z1.h[0] = (half_t)bn[2]; z1.h[1] = (half_t)bn[3];
      bh2[tid * 2] = z0.u;
      bh2[tid * 2 + 1] = z1.u;
      uint2 pk; pk.x = z0.u; pk.y = z1.u;
      *(uint2*)(BN + ((size_t)(t0 + tt) * 32 + b) * 256 + tid * 4) = pk;
      if (tt == TCH - 1) *(f32x4*)(bstate + b * 256 + tid * 4) = bn;
      if (t0 + tt == BPTT - 1) *(f32x4*)(bfinal + b * 256 + tid * 4) = bn;
    }
    __syncthreads();  // B2: guards partial reuse AND bh2 write->read
#pragma unroll
    for (int k = 0; k < 8; k++) cur[k] = nxt[k];
  }
}

// ------- fused top-level: [scan | M-GEMM | V-GEMM | decoder] by block range -------
// No min-waves clause (R11: (1024,8) forced VGPR=32 -> spills, 2.8x slower).
__global__ __launch_bounds__(1024) void fused_k(
    int scanN, int gemmN, int vN, const half_t* __restrict__ Msc,
    const float* __restrict__ Vbuf, int t0, const float* __restrict__ bin,
    float* __restrict__ bstate, half_t* __restrict__ BN,
    float* __restrict__ bfinal, const half_t* __restrict__ Ag,
    const half_t* __restrict__ Bg, half_t* __restrict__ Cg,
    const half_t* __restrict__ obsF, const half_t* __restrict__ WBh,
    float* __restrict__ Vout, int decRow0, const half_t* __restrict__ BNa,
    const half_t* __restrict__ B4, float* __restrict__ outp,
    const float* __restrict__ dec_b) {
  extern __shared__ char smem[];
  const int id = blockIdx.x;
  if (id < scanN) {
    scan_body(Msc, Vbuf, t0, bin, bstate, BN, bfinal, id, smem);
  } else if (id < scanN + gemmN) {
    const int g = id - scanN;
    gemmMC_body<0>(Ag, Bg, (void*)Cg, nullptr, g * 128, NH2, 0, smem);
  } else if (id < scanN + gemmN + vN) {
    const int v = id - scanN - gemmN;
    gemmMC_body<2>(obsF + (size_t)(v >> 1) * 256 * NHID, WBh,
                   (void*)(Vout + (size_t)(v >> 1) * 256 * 256), nullptr,
                   (v & 1) * 128, 256, 0, smem);
  } else {
    const int d = id - scanN - gemmN - vN;
    const int r0 = decRow0 + (d >> 4) * 256;
    gemmMC_body<3>(BNa + (size_t)r0 * 256, B4, (void*)(outp + (size_t)r0 * NTOK),
                   dec_b, (d & 15) * 128, NTOK, NTOK, smem);
  }
}

// ---------------- front: gemm1 split-K=4 only (512 blocks) ----------------
__global__ __launch_bounds__(256) void front_k(const half_t* __restrict__ Ahi,
                                               const half_t* __restrict__ Alo,
                                               const half_t* __restrict__ Bhi,
                                               const half_t* __restrict__ Blo,
                                               float* __restrict__ P) {
  extern __shared__ char fsm[];
  half_t* Ash = (half_t*)fsm;              // 8192 B
  half_t* Asl = (half_t*)(fsm + 8192);     // 8192 B
  half_t* Bsh = (half_t*)(fsm + 16384);    // 4096 B
  half_t* Bsl = (half_t*)(fsm + 20480);    // 4096 B
  const int id = blockIdx.x;
  const int kp = id & 3, r2 = id >> 2;
  const int bx = r2 & 7, by = r2 >> 3;
  const int row0 = bx * 128, col0 = by * 64, koff = kp * 512;
  const int tid = threadIdx.x;
  const int lane = tid & 63, wave = tid >> 6;
  const int wr = wave >> 1, wc = wave & 1;
  const int srow = tid >> 2, sseg = tid & 3;
  const size_t aoff = (size_t)(row0 + srow) * NTOKP + koff + sseg * 8;
  const size_t boff = (size_t)(col0 + srow) * NTOKP + koff + sseg * 8;
  const int fr = lane & 15, fq = lane >> 4;

  f32x4 acc[4][2];
#pragma unroll
  for (int m = 0; m < 4; m++)
#pragma unroll
    for (int n = 0; n < 2; n++) acc[m][n] = (f32x4)(0.0f);

  for (int k0 = 0; k0 < 512; k0 += 32) {
    f16x8 ah0 = *(const f16x8*)(Ahi + aoff + k0);
    f16x8 ah1 = *(const f16x8*)(Ahi + aoff + (size_t)64 * NTOKP + k0);
    f16x8 al0 = *(const f16x8*)(Alo + aoff + k0);
    f16x8 al1 = *(const f16x8*)(Alo + aoff + (size_t)64 * NTOKP + k0);
    f16x8 bh0 = *(const f16x8*)(Bhi + boff + k0);
    f16x8 bl0 = *(const f16x8*)(Blo + boff + k0);
    __syncthreads();
    *(f16x8*)(Ash + swz(srow, sseg * 8)) = ah0;
    *(f16x8*)(Ash + swz(srow + 64, sseg * 8)) = ah1;
    *(f16x8*)(Asl + swz(srow, sseg * 8)) = al0;
    *(f16x8*)(Asl + swz(srow + 64, sseg * 8)) = al1;
    *(f16x8*)(Bsh + swz(srow, sseg * 8)) = bh0;
    *(f16x8*)(Bsl + swz(srow, sseg * 8)) = bl0;
    __syncthreads();
    f16x8 afh[4], afl[4], bfh[2], bfl[2];
#pragma unroll
    for (int m = 0; m < 4; m++) {
      afh[m] = *(const f16x8*)(Ash + swz(wr * 64 + m * 16 + fr, fq * 8));
      afl[m] = *(const f16x8*)(Asl + swz(wr * 64 + m * 16 + fr, fq * 8));
    }
#pragma unroll
    for (int n = 0; n < 2; n++) {
      bfh[n] = *(const f16x8*)(Bsh + swz(wc * 32 + n * 16 + fr, fq * 8));
      bfl[n] = *(const f16x8*)(Bsl + swz(wc * 32 + n * 16 + fr, fq * 8));
    }
#pragma unroll
    for (int m = 0; m < 4; m++)
#pragma unroll
      for (int n = 0; n < 2; n++) {
        acc[m][n] = __builtin_amdgcn_mfma_f32_16x16x32_f16(afh[m], bfh[n], acc[m][n], 0, 0, 0);
        acc[m][n] = __builtin_amdgcn_mfma_f32_16x16x32_f16(afl[m], bfh[n], acc[m][n], 0, 0, 0);
        acc[m][n] = __builtin_amdgcn_mfma_f32_16x16x32_f16(afh[m], bfl[n], acc[m][n], 0, 0, 0);
      }
  }

  float* Pk = P + (size_t)kp * (NINP * (size_t)TB);
#pragma unroll
  for (int m = 0; m < 4; m++)
#pragma unroll
    for (int n = 0; n < 2; n++)
#pragma unroll
      for (int j = 0; j < 4; j++) {
        int gr = row0 + wr * 64 + m * 16 + fq * 4 + j;
        int gc = col0 + wc * 32 + n * 16 + fr;
        Pk[(size_t)gr * NINP + gc] = acc[m][n][j];
      }
}

// combine split-K partials: encA = f16(cos(sum_kp P + bias) * scale)
__global__ void rbf_combine_k(const float* __restrict__ P, const float* __restrict__ bias,
                              half_t* __restrict__ C) {
  int idx = blockIdx.x * 256 + threadIdx.x;
  int e0 = idx * 4;
  int col = e0 & (NINP - 1);
  f32x4 s = *(const f32x4*)(P + e0);
  s += *(const f32x4*)(P + (size_t)1 * TB * NINP + e0);
  s += *(const f32x4*)(P + (size_t)2 * TB * NINP + e0);
  s += *(const f32x4*)(P + (size_t)3 * TB * NINP + e0);
  const float RBF_SCALE = 0.04419417382415922f;  // sqrt(2)/sqrt(1024)
  f16x4 o;
#pragma unroll
  for (int j = 0; j < 4; j++) o[j] = (half_t)(cosf(s[j] + bias[col + j]) * RBF_SCALE);
  *(f16x4*)(C + e0) = o;
}

// ---------------- launch ----------------

extern "C" void kernel_launch(void* const* d_in, const int* in_sizes, int n_in,
                              void* d_out, int out_size, void* d_ws, size_t ws_size,
                              hipStream_t stream) {
  const float* input = (const float*)d_in[0];
  const float* b0 = (const float*)d_in[1];
  const float* RBF_w = (const float*)d_in[2];
  const float* RBF_b = (const float*)d_in[3];
  const float* emb_w = (const float*)d_in[4];
  const float* emb_b = (const float*)d_in[5];
  const float* wfef_w = (const float*)d_in[6];
  const float* wfef_b = (const float*)d_in[7];
  const float* dec_w = (const float*)d_in[8];
  const float* dec_b = (const float*)d_in[9];

  char* ws = (char*)d_ws;
  size_t off = 0;
  auto alloc = [&](size_t bytes) {
    void* p = ws + off;
    off += (bytes + 255) & ~(size_t)255;
    return p;
  };
  half_t* A1hi = (half_t*)alloc((size_t)TB * NTOKP * 2);
  half_t* A1lo = (half_t*)alloc((size_t)TB * NTOKP * 2);
  half_t* B1hi = (half_t*)alloc((size_t)NINP * NTOKP * 2);
  half_t* B1lo = (half_t*)alloc((size_t)NINP * NTOKP * 2);
  half_t* encA = (half_t*)alloc((size_t)TB * NINP * 2);
  half_t* B2 = (half_t*)alloc((size_t)NHID * NINP * 2);
  half_t* obsA = (half_t*)alloc((size_t)TB * NHID * 2);
  half_t* WBh = (half_t*)alloc((size_t)NHID * NHID * 2);
  half_t* B4 = (half_t*)alloc((size_t)2048 * NHID * 2);
  float* Vbuf = (float*)alloc((size_t)TB * NHID * 4);
  half_t* BN = (half_t*)alloc((size_t)TB * NHID * 2);
  float* bstate = (float*)alloc((size_t)BSZ * NHID * 4);
  half_t* WWT = (half_t*)alloc((size_t)NH2 * NHID * 2);
  half_t* Mmat = (half_t*)alloc((size_t)TB * NH2 * 2);
  if (off > ws_size) return;  // workspace too small: fail loudly

  // split-K partials alias the (not-yet-written) Mmat region: 4x 4MB f32
  float* Pk = (float*)Mmat;

  float* outp = (float*)d_out;
  float* bfinal = outp + (size_t)TB * NTOK;

  // D1: conversions + FULL wfef transpose (16.5KB tile: occupancy-free)
  cvtAll_k<<<4096 + 19712, 256, CVT_LDS, stream>>>(
      input, A1hi, A1lo, RBF_w, B1hi, B1lo, emb_w, wfef_b, dec_w, B2, WBh, B4,
      wfef_w, WWT);
  // D2: RBF GEMM (split-K) only
  front_k<<<512, 256, FRONT_LDS, stream>>>(A1hi, A1lo, B1hi, B1lo, Pk);
  // D3: combine + cos
  rbf_combine_k<<<(TB * NINP / 4) / 256, 256, 0, stream>>>(Pk, RBF_b, encA);
  // D4: obs = encoded @ emb_w.T + emb_b
  gemm128_k<1><<<dim3(8, 2), 256, 0, stream>>>(encA, B2, obsA, emb_b, NINP, NHID);

  // D5: M-GEMM chunk0 + V-GEMM (8 blocks)
  fused_k<<<520, 1024, FUSED_LDS, stream>>>(
      0, 512, 8, nullptr, Vbuf, 0, b0, bstate, BN, bfinal, obsA, WWT, Mmat, obsA,
      WBh, Vbuf, 0, BN, B4, outp, dec_b);
  // D6: scan0 || gemm1
  fused_k<<<544, 1024, FUSED_LDS, stream>>>(
      32, 512, 0, Mmat, Vbuf, 0, b0, bstate, BN, bfinal, obsA + (size_t)256 * NHID,
      WWT, Mmat + (size_t)256 * NH2, obsA, WBh, Vbuf, 0, BN, B4, outp, dec_b);
  // D7: scan1 || gemm2 || dec chunk0 (16 blocks)
  fused_k<<<560, 1024, FUSED_LDS, stream>>>(
      32, 512, 0, Mmat + (size_t)256 * NH2, Vbuf, TCH, bstate, bstate, BN, bfinal,
      obsA + (size_t)512 * NHID, WWT, Mmat + (size_t)512 * NH2, obsA, WBh, Vbuf, 0,
      BN, B4, outp, dec_b);
  // D8: scan2 || gemm3 || dec chunk1
  fused_k<<<560, 1024, FUSED_LDS, stream>>>(
      32, 512, 0, Mmat + (size_t)512 * NH2, Vbuf, 2 * TCH, bstate, bstate, BN,
      bfinal, obsA + (size_t)768 * NHID, WWT, Mmat + (size_t)768 * NH2, obsA, WBh,
      Vbuf, 256, BN, B4, outp, dec_b);
  // D9: scan3 || dec chunk2
  fused_k<<<48, 1024, FUSED_LDS, stream>>>(
      32, 0, 0, Mmat + (size_t)768 * NH2, Vbuf, 3 * TCH, bstate, bstate, BN, bfinal,
      nullptr, nullptr, nullptr, obsA, WBh, Vbuf, 512, BN, B4, outp, dec_b);
  // D10: dec chunk3 (16 blocks)
  fused_k<<<16, 1024, FUSED_LDS, stream>>>(
      0, 0, 0, nullptr, Vbuf, 0, bstate, bstate, BN, bfinal, nullptr, nullptr,
      nullptr, obsA, WBh, Vbuf, 768, BN, B4, outp, dec_b);
}

// Round 14
// 219.499 us; speedup vs baseline: 1.0646x; 1.0646x over previous
//
#include <hip/hip_runtime.h>
#include <hip/hip_fp16.h>
#include <math.h>

typedef _Float16 half_t;
typedef __attribute__((ext_vector_type(2))) _Float16 f16x2;
typedef __attribute__((ext_vector_type(4))) _Float16 f16x4;
typedef __attribute__((ext_vector_type(8))) _Float16 f16x8;
typedef __attribute__((ext_vector_type(4))) float f32x4;

#define BPTT 32
#define BSZ 32
#define NTOK 2000
#define NTOKP 2048
#define NINP 1024
#define NHID 256
#define TB 1024  /* BPTT*BSZ */
#define NH2 65536
#define TCH 8          /* t-steps per chunk -> 4 chunks of 256 rows */
#define FUSED_LDS 25600
#define FRONT_LDS 33024

// LDS swizzle for 32-half (64B) rows; bijective; same fn on write+read.
__device__ __forceinline__ int swz(int row, int hoff) {
  return (row * 32 + hoff) ^ ((row & 7) << 3);
}

// ---------------- wfef transpose body (v3, validated R9/R12) ----------------
__device__ __forceinline__ void wfefT_body(int p, const float* __restrict__ wfef,
                                           half_t* __restrict__ wwt, char* smem) {
  float* tile = (float*)smem;  // 32 x 258 f32 = 33024 B
  const int r = p >> 3, h0 = (p & 7) * 32;
  const int tid = threadIdx.x;
  const float* src = wfef + (size_t)(r * 256) * 256 + h0;
#pragma unroll
  for (int i = 0; i < 8; i++) {
    int q = i * 256 + tid;          // 2048 quads: 256 c x 8 qi
    int c = q >> 3, qi = q & 7;     // qi -> h = 4qi..4qi+3
    f32x4 v = *(const f32x4*)(src + (size_t)c * 256 + qi * 4);
#pragma unroll
    for (int k = 0; k < 4; k++) tile[(qi * 4 + k) * 258 + c] = v[k];
  }
  __syncthreads();
  const int c8 = (tid & 31) * 8, hr = tid >> 5;  // hr 0..7
#pragma unroll
  for (int i = 0; i < 4; i++) {
    int hh = i * 8 + hr;
    f32x4 u0 = *(const f32x4*)&tile[hh * 258 + c8];
    f32x4 u1 = *(const f32x4*)&tile[hh * 258 + c8 + 4];
    f16x8 o;
#pragma unroll
    for (int j = 0; j < 4; j++) {
      o[j] = (half_t)u0[j];
      o[j + 4] = (half_t)u1[j];
    }
    *(f16x8*)(wwt + ((size_t)(h0 + hh) * 256 + r) * 256 + c8) = o;
  }
}

// ---------------- merged conversions (one dispatch, NO LDS) ----------------
__global__ void cvtAll_k(const float* __restrict__ input, half_t* __restrict__ A1hi,
                         half_t* __restrict__ A1lo, const float* __restrict__ RBF_w,
                         half_t* __restrict__ B1hi, half_t* __restrict__ B1lo,
                         const float* __restrict__ emb_w,
                         const float* __restrict__ wfef_b,
                         const float* __restrict__ dec_w, half_t* __restrict__ B2,
                         half_t* __restrict__ WBh, half_t* __restrict__ B4) {
  int bid = blockIdx.x;
  if (bid < 16384) {
    const float* src;
    half_t *hi, *lo;
    int idx;
    if (bid < 8192) {
      src = input; hi = A1hi; lo = A1lo; idx = bid * 256 + threadIdx.x;
    } else {
      src = RBF_w; hi = B1hi; lo = B1lo; idx = (bid - 8192) * 256 + threadIdx.x;
    }
    int r = idx >> 11, c = idx & 2047;
    float v = (c < NTOK) ? src[(size_t)r * NTOK + c] : 0.f;
    half_t h = (half_t)v;
    hi[idx] = h;
    lo[idx] = (half_t)(v - (float)h);
    return;
  }
  int i = (bid - 16384) * 256 + threadIdx.x;
  if (i < 262144) { B2[i] = (half_t)emb_w[i]; return; }
  i -= 262144;
  if (i < 65536) { WBh[i] = (half_t)wfef_b[i]; return; }
  i -= 65536;
  int r = i >> 8, c = i & 255;
  B4[i] = (half_t)((r < NTOK) ? dec_w[(size_t)r * 256 + c] : 0.f);
}

// ---------------- 128x128 fp16 GEMM (256 thr), C = A @ B^T ----------------
// EP: 1 = half store (acc+bias) [obs]
template <int EP>
__global__ __launch_bounds__(256) void gemm128_k(const half_t* __restrict__ A,
                                                 const half_t* __restrict__ B,
                                                 void* __restrict__ C,
                                                 const float* __restrict__ bias, int K,
                                                 int ldc) {
  __shared__ half_t As[128 * 32];
  __shared__ half_t Bs[128 * 32];
  const int tid = threadIdx.x;
  const int lane = tid & 63, wave = tid >> 6;
  const int wr = wave >> 1, wc = wave & 1;
  const int row0 = blockIdx.x * 128, col0 = blockIdx.y * 128;
  const int srow = tid >> 2, sseg = tid & 3;
  const size_t aoff = (size_t)(row0 + srow) * K + sseg * 8;
  const size_t boff = (size_t)(col0 + srow) * K + sseg * 8;
  const int fr = lane & 15, fq = lane >> 4;

  f32x4 acc[4][4];
#pragma unroll
  for (int m = 0; m < 4; m++)
#pragma unroll
    for (int n = 0; n < 4; n++) acc[m][n] = (f32x4)(0.0f);

  for (int k0 = 0; k0 < K; k0 += 32) {
    f16x8 a0 = *(const f16x8*)(A + aoff + k0);
    f16x8 a1 = *(const f16x8*)(A + aoff + (size_t)64 * K + k0);
    f16x8 b0 = *(const f16x8*)(B + boff + k0);
    f16x8 b1 = *(const f16x8*)(B + boff + (size_t)64 * K + k0);
    __syncthreads();
    *(f16x8*)(As + swz(srow, sseg * 8)) = a0;
    *(f16x8*)(As + swz(srow + 64, sseg * 8)) = a1;
    *(f16x8*)(Bs + swz(srow, sseg * 8)) = b0;
    *(f16x8*)(Bs + swz(srow + 64, sseg * 8)) = b1;
    __syncthreads();
    f16x8 af[4], bf[4];
#pragma unroll
    for (int m = 0; m < 4; m++)
      af[m] = *(const f16x8*)(As + swz(wr * 64 + m * 16 + fr, fq * 8));
#pragma unroll
    for (int n = 0; n < 4; n++)
      bf[n] = *(const f16x8*)(Bs + swz(wc * 64 + n * 16 + fr, fq * 8));
#pragma unroll
    for (int m = 0; m < 4; m++)
#pragma unroll
      for (int n = 0; n < 4; n++)
        acc[m][n] = __builtin_amdgcn_mfma_f32_16x16x32_f16(af[m], bf[n], acc[m][n], 0, 0, 0);
  }

#pragma unroll
  for (int m = 0; m < 4; m++)
#pragma unroll
    for (int n = 0; n < 4; n++)
#pragma unroll
      for (int j = 0; j < 4; j++) {
        int gr = row0 + wr * 64 + m * 16 + fq * 4 + j;
        int gc = col0 + wc * 64 + n * 16 + fr;
        ((half_t*)C)[(size_t)gr * ldc + gc] = (half_t)(acc[m][n][j] + bias[gc]);
      }
}

// ---------------- tall-thin GEMM body: 256 rows x 128 cols, K=256, 1024 thr ----
// EP: 0 = half store (M precompute, ldc=NH2); 2 = f32 store (V); 3 = f32 + bias,
// col guard (decoder)
template <int EP>
__device__ __forceinline__ void gemmMC_body(const half_t* __restrict__ A,
                                            const half_t* __restrict__ B,
                                            void* __restrict__ C,
                                            const float* __restrict__ bias, int col0,
                                            int ldc, int nvalid, char* smem) {
  half_t* As = (half_t*)smem;            // 256x32 halfs = 16384 B
  half_t* Bs = (half_t*)(smem + 16384);  // 128x32 halfs = 8192 B
  const int tid = threadIdx.x;
  const int lane = tid & 63, wave = tid >> 6;  // 16 waves: 4 row x 4 col
  const int wr = wave >> 2, wc = wave & 3;     // wave tile 64 rows x 32 cols
  const int srow = tid >> 2, sseg = tid & 3;
  const int fr = lane & 15, fq = lane >> 4;
  const size_t aoff = (size_t)srow * 256 + sseg * 8;
  const size_t boff = (size_t)(col0 + (srow & 127)) * 256 + sseg * 8;

  f32x4 acc[4][2];
#pragma unroll
  for (int m = 0; m < 4; m++)
#pragma unroll
    for (int n = 0; n < 2; n++) acc[m][n] = (f32x4)(0.0f);

  for (int k0 = 0; k0 < 256; k0 += 32) {
    f16x8 a0 = *(const f16x8*)(A + aoff + k0);
    f16x8 b0;
    if (tid < 512) b0 = *(const f16x8*)(B + boff + k0);
    __syncthreads();
    *(f16x8*)(As + swz(srow, sseg * 8)) = a0;
    if (tid < 512) *(f16x8*)(Bs + swz(srow, sseg * 8)) = b0;
    __syncthreads();
    f16x8 af[4], bf[2];
#pragma unroll
    for (int m = 0; m < 4; m++)
      af[m] = *(const f16x8*)(As + swz(wr * 64 + m * 16 + fr, fq * 8));
#pragma unroll
    for (int n = 0; n < 2; n++)
      bf[n] = *(const f16x8*)(Bs + swz(wc * 32 + n * 16 + fr, fq * 8));
#pragma unroll
    for (int m = 0; m < 4; m++)
#pragma unroll
      for (int n = 0; n < 2; n++)
        acc[m][n] = __builtin_amdgcn_mfma_f32_16x16x32_f16(af[m], bf[n], acc[m][n], 0, 0, 0);
  }

#pragma unroll
  for (int m = 0; m < 4; m++)
#pragma unroll
    for (int n = 0; n < 2; n++)
#pragma unroll
      for (int j = 0; j < 4; j++) {
        int gr = wr * 64 + m * 16 + fq * 4 + j;
        int gc = col0 + wc * 32 + n * 16 + fr;
        if (EP == 0) {
          ((half_t*)C)[(size_t)gr * ldc + gc] = (half_t)acc[m][n][j];
        } else if (EP == 2) {
          ((float*)C)[(size_t)gr * ldc + gc] = acc[m][n][j];
        } else {
          if (gc < nvalid)
            ((float*)C)[(size_t)gr * ldc + gc] = acc[m][n][j] + bias[gc];
        }
      }
}

// ---------------- scan body: TCH steps, 1024 threads, 2 barriers/step ----------
// Phase 2 on ONE wave (tid<64, 4 r's/lane): 256-r sumsq completes in-wave via
// shfl_xor; single B2 guards partial reuse AND bh2 write->read.
__device__ void scan_body(const half_t* __restrict__ Mc, const float* __restrict__ V,
                          int t0, const float* __restrict__ bin,
                          float* __restrict__ bstate, half_t* __restrict__ BN,
                          float* __restrict__ bfinal, int b, char* smem) {
  float(*Vs)[256] = (float(*)[256])smem;                  // 8192 B
  float(*partial)[260] = (float(*)[260])(smem + 8192);    // 16640 B
  unsigned* bh2 = (unsigned*)(smem + 24832);              // 512 B
  const int tid = threadIdx.x;
  const int hh = tid >> 6, lane = tid & 63;
  const int hpar = lane >> 5, r8 = (lane & 31) * 8;

  if (tid < TCH * 64) {
    int vr = tid >> 6;
    *(f32x4*)&Vs[vr][lane * 4] =
        *(const f32x4*)(V + ((size_t)(t0 + vr) * 32 + b) * 256 + lane * 4);
  }
  if (tid < 128) {
    const float* bs = bin + b * 256 + tid * 2;
    union { f16x2 h; unsigned u; } z;
    z.h[0] = (half_t)bs[0];
    z.h[1] = (half_t)bs[1];
    bh2[tid] = z.u;
  }

  // lane covers h = hh*16 + hpar + 2k (k=0..7), r in [r8, r8+8)
  const half_t* mbase = Mc + (size_t)b * NH2 + (size_t)(hh * 16 + hpar) * 256 + r8;
  f16x8 cur[8], nxt[8];
#pragma unroll
  for (int k = 0; k < 8; k++) cur[k] = *(const f16x8*)(mbase + k * 512);
  __syncthreads();

  for (int tt = 0; tt < TCH; tt++) {
    const int tn = (tt < TCH - 1) ? tt + 1 : TCH - 1;
    const half_t* mb2 = mbase + (size_t)tn * 32 * NH2;
#pragma unroll
    for (int k = 0; k < 8; k++) nxt[k] = *(const f16x8*)(mb2 + k * 512);

    uint4 q0 = *(const uint4*)&bh2[hh * 8];
    uint4 q1 = *(const uint4*)&bh2[hh * 8 + 4];
    unsigned bu[8] = {q0.x, q0.y, q0.z, q0.w, q1.x, q1.y, q1.z, q1.w};
    const int sh = hpar * 16;
    half_t hv[8];
#pragma unroll
    for (int k = 0; k < 8; k++)
      hv[k] = __builtin_bit_cast(half_t, (unsigned short)(bu[k] >> sh));

    float a[8] = {0.f, 0.f, 0.f, 0.f, 0.f, 0.f, 0.f, 0.f};
#pragma unroll
    for (int k = 0; k < 8; k++)
#pragma unroll
      for (int j = 0; j < 8; j++) a[j] += (float)cur[k][j] * (float)hv[k];
#pragma unroll
    for (int j = 0; j < 8; j++) a[j] += __shfl_xor(a[j], 32);
    f32x4 st = hpar ? (f32x4){a[4], a[5], a[6], a[7]} : (f32x4){a[0], a[1], a[2], a[3]};
    *(f32x4*)&partial[hh][r8 + hpar * 4] = st;
    __syncthreads();  // B1: partials ready

    if (tid < 64) {  // single-wave normalize: lane owns r = tid*4 .. tid*4+3
      f32x4 s = *(const f32x4*)&Vs[tt][tid * 4];
#pragma unroll
      for (int g = 0; g < 16; g++) s += *(const f32x4*)&partial[g][tid * 4];
      float sq = s[0] * s[0] + s[1] * s[1] + s[2] * s[2] + s[3] * s[3];
#pragma unroll
      for (int o = 32; o > 0; o >>= 1) sq += __shfl_xor(sq, o);
      float inv = 1.0f / sqrtf(sq);
      f32x4 bn = {s[0] * inv, s[1] * inv, s[2] * inv, s[3] * inv};
      union { f16x2 h; unsigned u; } z0, z1;
      z0.h[0] = (half_t)bn[0]; z0.h[1] = (half_t)bn[1];
      z1.h[0] = (half_t)bn[2]; z1.h[1] = (half_t)bn[3];
      bh2[tid * 2] = z0.u;
      bh2[tid * 2 + 1] = z1.u;
      uint2 pk; pk.x = z0.u; pk.y = z1.u;
      *(uint2*)(BN + ((size_t)(t0 + tt) * 32 + b) * 256 + tid * 4) = pk;
      if (tt == TCH - 1) *(f32x4*)(bstate + b * 256 + tid * 4) = bn;
      if (t0 + tt == BPTT - 1) *(f32x4*)(bfinal + b * 256 + tid * 4) = bn;
    }
    __syncthreads();  // B2: guards partial reuse AND bh2 write->read
#pragma unroll
    for (int k = 0; k < 8; k++) cur[k] = nxt[k];
  }
}

// ------- fused top-level: [scan | M-GEMM | V-GEMM | decoder] by block range -------
// NOTE: no min-waves clause — R11's (1024,8) forced VGPR=32 and spilled the
// GEMM role (63us dispatches). Compiler picks ~56-64 VGPR naturally.
__global__ __launch_bounds__(1024) void fused_k(
    int scanN, int gemmN, int vN, const half_t* __restrict__ Msc,
    const float* __restrict__ Vbuf, int t0, const float* __restrict__ bin,
    float* __restrict__ bstate, half_t* __restrict__ BN,
    float* __restrict__ bfinal, const half_t* __restrict__ Ag,
    const half_t* __restrict__ Bg, half_t* __restrict__ Cg,
    const half_t* __restrict__ obsF, const half_t* __restrict__ WBh,
    float* __restrict__ Vout, int decRow0, const half_t* __restrict__ BNa,
    const half_t* __restrict__ B4, float* __restrict__ outp,
    const float* __restrict__ dec_b) {
  extern __shared__ char smem[];
  const int id = blockIdx.x;
  if (id < scanN) {
    scan_body(Msc, Vbuf, t0, bin, bstate, BN, bfinal, id, smem);
  } else if (id < scanN + gemmN) {
    const int g = id - scanN;
    gemmMC_body<0>(Ag, Bg, (void*)Cg, nullptr, g * 128, NH2, 0, smem);
  } else if (id < scanN + gemmN + vN) {
    const int v = id - scanN - gemmN;
    gemmMC_body<2>(obsF + (size_t)(v >> 1) * 256 * NHID, WBh,
                   (void*)(Vout + (size_t)(v >> 1) * 256 * 256), nullptr,
                   (v & 1) * 128, 256, 0, smem);
  } else {
    const int d = id - scanN - gemmN - vN;
    const int r0 = decRow0 + (d >> 4) * 256;
    gemmMC_body<3>(BNa + (size_t)r0 * 256, B4, (void*)(outp + (size_t)r0 * NTOK),
                   dec_b, (d & 15) * 128, NTOK, NTOK, smem);
  }
}

// ---------------- front: gemm1 split-K=4 (512) + wfef transpose (2048) ----
__global__ __launch_bounds__(256) void front_k(const half_t* __restrict__ Ahi,
                                               const half_t* __restrict__ Alo,
                                               const half_t* __restrict__ Bhi,
                                               const half_t* __restrict__ Blo,
                                               float* __restrict__ P,
                                               const float* __restrict__ wfef,
                                               half_t* __restrict__ wwt) {
  extern __shared__ char fsm[];
  if (blockIdx.x >= 512) {
    wfefT_body(blockIdx.x - 512, wfef, wwt, fsm);
    return;
  }
  // split-precision RBF GEMM, 128x64 tile, split-K=4
  half_t* Ash = (half_t*)fsm;              // 8192 B
  half_t* Asl = (half_t*)(fsm + 8192);     // 8192 B
  half_t* Bsh = (half_t*)(fsm + 16384);    // 4096 B
  half_t* Bsl = (half_t*)(fsm + 20480);    // 4096 B
  const int id = blockIdx.x;
  const int kp = id & 3, r2 = id >> 2;
  const int bx = r2 & 7, by = r2 >> 3;
  const int row0 = bx * 128, col0 = by * 64, koff = kp * 512;
  const int tid = threadIdx.x;
  const int lane = tid & 63, wave = tid >> 6;
  const int wr = wave >> 1, wc = wave & 1;
  const int srow = tid >> 2, sseg = tid & 3;
  const size_t aoff = (size_t)(row0 + srow) * NTOKP + koff + sseg * 8;
  const size_t boff = (size_t)(col0 + srow) * NTOKP + koff + sseg * 8;
  const int fr = lane & 15, fq = lane >> 4;

  f32x4 acc[4][2];
#pragma unroll
  for (int m = 0; m < 4; m++)
#pragma unroll
    for (int n = 0; n < 2; n++) acc[m][n] = (f32x4)(0.0f);

  for (int k0 = 0; k0 < 512; k0 += 32) {
    f16x8 ah0 = *(const f16x8*)(Ahi + aoff + k0);
    f16x8 ah1 = *(const f16x8*)(Ahi + aoff + (size_t)64 * NTOKP + k0);
    f16x8 al0 = *(const f16x8*)(Alo + aoff + k0);
    f16x8 al1 = *(const f16x8*)(Alo + aoff + (size_t)64 * NTOKP + k0);
    f16x8 bh0 = *(const f16x8*)(Bhi + boff + k0);
    f16x8 bl0 = *(const f16x8*)(Blo + boff + k0);
    __syncthreads();
    *(f16x8*)(Ash + swz(srow, sseg * 8)) = ah0;
    *(f16x8*)(Ash + swz(srow + 64, sseg * 8)) = ah1;
    *(f16x8*)(Asl + swz(srow, sseg * 8)) = al0;
    *(f16x8*)(Asl + swz(srow + 64, sseg * 8)) = al1;
    *(f16x8*)(Bsh + swz(srow, sseg * 8)) = bh0;
    *(f16x8*)(Bsl + swz(srow, sseg * 8)) = bl0;
    __syncthreads();
    f16x8 afh[4], afl[4], bfh[2], bfl[2];
#pragma unroll
    for (int m = 0; m < 4; m++) {
      afh[m] = *(const f16x8*)(Ash + swz(wr * 64 + m * 16 + fr, fq * 8));
      afl[m] = *(const f16x8*)(Asl + swz(wr * 64 + m * 16 + fr, fq * 8));
    }
#pragma unroll
    for (int n = 0; n < 2; n++) {
      bfh[n] = *(const f16x8*)(Bsh + swz(wc * 32 + n * 16 + fr, fq * 8));
      bfl[n] = *(const f16x8*)(Bsl + swz(wc * 32 + n * 16 + fr, fq * 8));
    }
#pragma unroll
    for (int m = 0; m < 4; m++)
#pragma unroll
      for (int n = 0; n < 2; n++) {
        acc[m][n] = __builtin_amdgcn_mfma_f32_16x16x32_f16(afh[m], bfh[n], acc[m][n], 0, 0, 0);
        acc[m][n] = __builtin_amdgcn_mfma_f32_16x16x32_f16(afl[m], bfh[n], acc[m][n], 0, 0, 0);
        acc[m][n] = __builtin_amdgcn_mfma_f32_16x16x32_f16(afh[m], bfl[n], acc[m][n], 0, 0, 0);
      }
  }

  float* Pk = P + (size_t)kp * (NINP * (size_t)TB);
#pragma unroll
  for (int m = 0; m < 4; m++)
#pragma unroll
    for (int n = 0; n < 2; n++)
#pragma unroll
      for (int j = 0; j < 4; j++) {
        int gr = row0 + wr * 64 + m * 16 + fq * 4 + j;
        int gc = col0 + wc * 32 + n * 16 + fr;
        Pk[(size_t)gr * NINP + gc] = acc[m][n][j];
      }
}

// combine split-K partials: encA = f16(cos(sum_kp P + bias) * scale)
__global__ void rbf_combine_k(const float* __restrict__ P, const float* __restrict__ bias,
                              half_t* __restrict__ C) {
  int idx = blockIdx.x * 256 + threadIdx.x;
  int e0 = idx * 4;
  int col = e0 & (NINP - 1);
  f32x4 s = *(const f32x4*)(P + e0);
  s += *(const f32x4*)(P + (size_t)1 * TB * NINP + e0);
  s += *(const f32x4*)(P + (size_t)2 * TB * NINP + e0);
  s += *(const f32x4*)(P + (size_t)3 * TB * NINP + e0);
  const float RBF_SCALE = 0.04419417382415922f;  // sqrt(2)/sqrt(1024)
  f16x4 o;
#pragma unroll
  for (int j = 0; j < 4; j++) o[j] = (half_t)(cosf(s[j] + bias[col + j]) * RBF_SCALE);
  *(f16x4*)(C + e0) = o;
}

// ---------------- launch ----------------

extern "C" void kernel_launch(void* const* d_in, const int* in_sizes, int n_in,
                              void* d_out, int out_size, void* d_ws, size_t ws_size,
                              hipStream_t stream) {
  const float* input = (const float*)d_in[0];
  const float* b0 = (const float*)d_in[1];
  const float* RBF_w = (const float*)d_in[2];
  const float* RBF_b = (const float*)d_in[3];
  const float* emb_w = (const float*)d_in[4];
  const float* emb_b = (const float*)d_in[5];
  const float* wfef_w = (const float*)d_in[6];
  const float* wfef_b = (const float*)d_in[7];
  const float* dec_w = (const float*)d_in[8];
  const float* dec_b = (const float*)d_in[9];

  char* ws = (char*)d_ws;
  size_t off = 0;
  auto alloc = [&](size_t bytes) {
    void* p = ws + off;
    off += (bytes + 255) & ~(size_t)255;
    return p;
  };
  half_t* A1hi = (half_t*)alloc((size_t)TB * NTOKP * 2);
  half_t* A1lo = (half_t*)alloc((size_t)TB * NTOKP * 2);
  half_t* B1hi = (half_t*)alloc((size_t)NINP * NTOKP * 2);
  half_t* B1lo = (half_t*)alloc((size_t)NINP * NTOKP * 2);
  half_t* encA = (half_t*)alloc((size_t)TB * NINP * 2);
  half_t* B2 = (half_t*)alloc((size_t)NHID * NINP * 2);
  half_t* obsA = (half_t*)alloc((size_t)TB * NHID * 2);
  half_t* WBh = (half_t*)alloc((size_t)NHID * NHID * 2);
  half_t* B4 = (half_t*)alloc((size_t)2048 * NHID * 2);
  float* Vbuf = (float*)alloc((size_t)TB * NHID * 4);
  half_t* BN = (half_t*)alloc((size_t)TB * NHID * 2);
  float* bstate = (float*)alloc((size_t)BSZ * NHID * 4);
  half_t* WWT = (half_t*)alloc((size_t)NH2 * NHID * 2);
  half_t* Mmat = (half_t*)alloc((size_t)TB * NH2 * 2);
  if (off > ws_size) return;  // workspace too small: fail loudly

  // split-K partials alias the (not-yet-written) Mmat region: 4x 4MB f32
  float* Pk = (float*)Mmat;

  float* outp = (float*)d_out;
  float* bfinal = outp + (size_t)TB * NTOK;

  // D1: all conversions (no LDS)
  cvtAll_k<<<19712, 256, 0, stream>>>(input, A1hi, A1lo, RBF_w, B1hi, B1lo, emb_w,
                                      wfef_b, dec_w, B2, WBh, B4);
  // D2: RBF GEMM (split-K) + wfef transpose v3 fused
  front_k<<<512 + 2048, 256, FRONT_LDS, stream>>>(A1hi, A1lo, B1hi, B1lo, Pk,
                                                  wfef_w, WWT);
  // D3: combine + cos
  rbf_combine_k<<<(TB * NINP / 4) / 256, 256, 0, stream>>>(Pk, RBF_b, encA);
  // D4: obs = encoded @ emb_w.T + emb_b
  gemm128_k<1><<<dim3(8, 2), 256, 0, stream>>>(encA, B2, obsA, emb_b, NINP, NHID);

  // D5: M-GEMM chunk0 + V-GEMM (8 blocks)
  fused_k<<<520, 1024, FUSED_LDS, stream>>>(
      0, 512, 8, nullptr, Vbuf, 0, b0, bstate, BN, bfinal, obsA, WWT, Mmat, obsA,
      WBh, Vbuf, 0, BN, B4, outp, dec_b);
  // D6: scan0 || gemm1
  fused_k<<<544, 1024, FUSED_LDS, stream>>>(
      32, 512, 0, Mmat, Vbuf, 0, b0, bstate, BN, bfinal, obsA + (size_t)256 * NHID,
      WWT, Mmat + (size_t)256 * NH2, obsA, WBh, Vbuf, 0, BN, B4, outp, dec_b);
  // D7: scan1 || gemm2 || dec chunk0 (16 blocks)
  fused_k<<<560, 1024, FUSED_LDS, stream>>>(
      32, 512, 0, Mmat + (size_t)256 * NH2, Vbuf, TCH, bstate, bstate, BN, bfinal,
      obsA + (size_t)512 * NHID, WWT, Mmat + (size_t)512 * NH2, obsA, WBh, Vbuf, 0,
      BN, B4, outp, dec_b);
  // D8: scan2 || gemm3 || dec chunk1
  fused_k<<<560, 1024, FUSED_LDS, stream>>>(
      32, 512, 0, Mmat + (size_t)512 * NH2, Vbuf, 2 * TCH, bstate, bstate, BN,
      bfinal, obsA + (size_t)768 * NHID, WWT, Mmat + (size_t)768 * NH2, obsA, WBh,
      Vbuf, 256, BN, B4, outp, dec_b);
  // D9: scan3 || dec chunk2
  fused_k<<<48, 1024, FUSED_LDS, stream>>>(
      32, 0, 0, Mmat + (size_t)768 * NH2, Vbuf, 3 * TCH, bstate, bstate, BN, bfinal,
      nullptr, nullptr, nullptr, obsA, WBh, Vbuf, 512, BN, B4, outp, dec_b);
  // D10: dec chunk3 (16 blocks)
  fused_k<<<16, 1024, FUSED_LDS, stream>>>(
      0, 0, 0, nullptr, Vbuf, 0, bstate, bstate, BN, bfinal, nullptr, nullptr,
      nullptr, obsA, WBh, Vbuf, 768, BN, B4, outp, dec_b);
}